// Round 8
// baseline (2158.251 us; speedup 1.0000x reference)
//
#include <hip/hip_runtime.h>
#include <hip/hip_fp16.h>

#define AGENT __HIP_MEMORY_SCOPE_AGENT

typedef _Float16 v8h __attribute__((ext_vector_type(8)));
typedef float    v4f __attribute__((ext_vector_type(4)));
typedef unsigned long long u64;

// ---- workspace map (bytes) ----
#define OFF_KEYSH  0UL            // __half [128][128][256] (b,u,s)   = 8,388,608
#define OFF_WBF    8388608UL      // __half Wb B-frags, 4u+g perm: 32kt x 64nt x 64lane x 8 = 2,097,152
#define OFF_WCF    10485760UL     // __half Wc B-frags, 4u+g perm: 16kt x 64nt x 64lane x 8 = 1,048,576
#define OFF_W1T    11534336UL     // float [128 u][512 e]             =   262,144
#define OFF_CTXU   11796480UL     // float [128 b][2 half][512 e]     =   524,288
#define OFF_SU     12320768UL     // float [128 b][2 half]            =     1,024
#define OFF_H1     12321792UL     // uint  [2][128][128]              =   131,072
#define OFF_H2     12452864UL     // uint  [2][128][128]              =   131,072
#define OFF_CNT    12583936UL     // int[4 grp][256]: [0..143] masters, [160/176] subs = 4,096
#define WS_CORE    12588032UL
#define OFF_ENCH   12588032UL     // __half [128][256][512]           = 33,554,432
#define WS_FULL    46142464UL

static __device__ __forceinline__ float fast_tanh(float x){
    float e = __expf(2.0f*x);
    return 1.0f - 2.0f*__builtin_amdgcn_rcpf(e + 1.0f);
}
static __device__ __forceinline__ float fast_sigm(float x){
    return __builtin_amdgcn_rcpf(1.0f + __expf(-x));
}

// Group-local grid barrier: 64 blocks per group, 4 independent groups.
// Arrival: 2 sub-counters x 32 blocks (distinct 64-B lines); combiner
// (old==31) resets its sub-line then bumps the group's per-phase master;
// poll single master line (<2). Monotone masters, fresh per phase.
// s_waitcnt(0) drains relaxed agent stores pre-arrival (proven r4 pattern).
static __device__ __forceinline__ void gbar(int* cnt, int grp, int idx){
    __builtin_amdgcn_s_waitcnt(0);
    __syncthreads();
    if(threadIdx.x == 0){
        int* base = cnt + (grp << 8);
        int* sub  = base + 160 + (((blockIdx.x >> 5) & 1) << 4);
        int old = __hip_atomic_fetch_add(sub, 1, __ATOMIC_RELAXED, AGENT);
        if(old == 31){
            __hip_atomic_store(sub, 0, __ATOMIC_RELAXED, AGENT);
            __builtin_amdgcn_s_waitcnt(0);
            __hip_atomic_fetch_add(&base[idx], 1, __ATOMIC_RELAXED, AGENT);
        }
        while(__hip_atomic_load(&base[idx], __ATOMIC_RELAXED, AGENT) < 2)
            __builtin_amdgcn_s_sleep(1);
    }
    __syncthreads();
}

// ---------------- setup: permuted MFMA B-frag weights, W1t, state packing, counters, encH
// WbF half idx = ((kt*64 + nt)*64 + lane)*8 + j ; c = nt*16 + (lane&15) (4u+g space)
//   n_raw = (c&3)*256 + (c>>2) ; k = kt*32 + (lane>>4)*8 + j
//   k<768 -> Wx1[k][n_raw] ([emb|ctx] rows), else Wh1[k-768][n_raw]
// WcF: kt 0..15 ; k<256 -> Wx2[k][n_raw], else Wh2[k-256][n_raw]  ([h1|h2])
__global__ __launch_bounds__(256) void setup_kernel(
    const float* __restrict__ Wx1, const float* __restrict__ Wh1,
    const float* __restrict__ Wx2, const float* __restrict__ Wh2,
    const float* __restrict__ W1,
    const float* __restrict__ h1_in, const float* __restrict__ h2_in,
    const float* __restrict__ enc,
    __half* __restrict__ WbF, __half* __restrict__ WcF, float* __restrict__ W1t,
    unsigned int* __restrict__ h1d, unsigned int* __restrict__ h2d,
    int* __restrict__ cnt, __half* __restrict__ encH, long long total)
{
    long long id0 = (long long)blockIdx.x*blockDim.x + threadIdx.x;
    long long stride = (long long)gridDim.x*blockDim.x;
    for(long long id = id0; id < total; id += stride){
        if(id < 1048576LL){                         // WbF
            int j = (int)(id & 7), lane = (int)((id >> 3) & 63);
            int tile = (int)(id >> 9);
            int nt = tile & 63, kt = tile >> 6;
            int c = nt*16 + (lane & 15);
            int n = (c & 3)*256 + (c >> 2);
            int k = kt*32 + (lane >> 4)*8 + j;
            float v = (k < 768) ? Wx1[k*1024 + n] : Wh1[(k-768)*1024 + n];
            WbF[id] = __float2half(v);
        } else if(id < 1572864LL){                  // WcF
            long long i2 = id - 1048576LL;
            int j = (int)(i2 & 7), lane = (int)((i2 >> 3) & 63);
            int tile = (int)(i2 >> 9);
            int nt = tile & 63, kt = tile >> 6;
            int c = nt*16 + (lane & 15);
            int n = (c & 3)*256 + (c >> 2);
            int k = kt*32 + (lane >> 4)*8 + j;
            float v = (k < 256) ? Wx2[k*1024 + n] : Wh2[(k-256)*1024 + n];
            WcF[i2] = __float2half(v);
        } else if(id < 1638400LL){                  // W1t[u][e]
            long long i3 = id - 1572864LL;
            int u = (int)(i3 >> 9), e = (int)(i3 & 511);
            W1t[i3] = W1[e*128 + u];
        } else if(id < 1654784LL){                  // h1d parity 0, packed fp16 pairs
            long long i4 = id - 1638400LL;
            int b = (int)(i4 >> 7), j = (int)(i4 & 127);
            __half2 p = __floats2half2_rn(h1_in[b*256 + 2*j], h1_in[b*256 + 2*j + 1]);
            h1d[i4] = __builtin_bit_cast(unsigned int, p);
        } else if(id < 1671168LL){                  // h2d parity 0
            long long i5 = id - 1654784LL;
            int b = (int)(i5 >> 7), j = (int)(i5 & 127);
            __half2 p = __floats2half2_rn(h2_in[b*256 + 2*j], h2_in[b*256 + 2*j + 1]);
            h2d[i5] = __builtin_bit_cast(unsigned int, p);
        } else if(id < 1672192LL){                  // cnt[1024] zero
            cnt[(int)(id - 1671168LL)] = 0;
        } else {                                    // encH
            long long i6 = id - 1672192LL;
            encH[i6] = __float2half(enc[i6]);
        }
    }
}

// ---------------- keys = enc @ W1 + b1, transposed fp16 keysH[b][u][s]
__global__ __launch_bounds__(256) void keys_kernel(
    const float* __restrict__ enc, const float* __restrict__ W1t,
    const float* __restrict__ b1, __half* __restrict__ keysH)
{
    const int bb = blockIdx.x;            // 1024 blocks
    const int b  = bb >> 3, sq = bb & 7;
    const int tid = threadIdx.x;
    const int u = tid & 127, sh = tid >> 7;
    const int s0 = sq*32 + sh*16;
    float acc[16];
    #pragma unroll
    for(int i = 0; i < 16; ++i) acc[i] = 0.0f;
    const float* wp = W1t + (size_t)u*512;
    const float* xp = enc + (size_t)(b*256 + s0)*512;
    for(int e = 0; e < 512; e += 4){
        float4 wv = *(const float4*)(wp + e);
        #pragma unroll
        for(int i = 0; i < 16; ++i){
            float4 xv = *(const float4*)(xp + (size_t)i*512 + e);
            acc[i] += wv.x*xv.x + wv.y*xv.y + wv.z*xv.z + wv.w*xv.w;
        }
    }
    const float bu = b1[u];
    __half* op = keysH + (size_t)(b*128 + u)*256 + s0;
    #pragma unroll
    for(int i = 0; i < 16; ++i) op[i] = __float2half(acc[i] + bu);
}

// ---------------- persistent decoder: 256 blocks x 1024 threads (~1/CU)
// GROUP-LOCAL decomposition: gq = bid>>6 owns batches 32gq..32gq+31; j = bid&63.
// Attention: ab = 32gq + (j>>1), s-half sh = j&1; deferred softmax norm
// (no max pass; unnormalized ctx partials + partial sums via MALL).
// LSTM: NT = j owns gate-cols 16j.. (4u+g perm) for the group's 32 rows;
// two 16-row tiles by parallel 8-wave groups (8-way K-split). All three
// per-step exchanges (CTXU/SU, h1, h2) are group-internal -> 64-block
// barriers, 4 independent groups. Weights register-resident as B-frags.
__global__ __launch_bounds__(1024) void decoder_v8(
    const float* __restrict__ xdec, const float* __restrict__ embW, const float* __restrict__ embb,
    const float* __restrict__ W2, const float* __restrict__ b2,
    const float* __restrict__ V, const float* __restrict__ bVp,
    const float* __restrict__ Wo, const float* __restrict__ bop,
    const float* __restrict__ bl1, const float* __restrict__ bl2,
    const float* __restrict__ c1_in, const float* __restrict__ c2_in,
    const float* __restrict__ enc, const __half* __restrict__ encH,
    const __half* __restrict__ keysH,
    const __half* __restrict__ WbF, const __half* __restrict__ WcF,
    float* CTXU, float* SU,
    unsigned int* h1d, unsigned int* h2d,
    int* cnt, float* __restrict__ out, int useEncH)
{
    const int tid  = threadIdx.x;
    const int bid  = blockIdx.x;
    const int gq   = bid >> 6;                 // group (32 batches)
    const int j    = bid & 63;                 // block within group
    const int ab   = 32*gq + (j >> 1);         // attention batch
    const int sh   = j & 1;                    // s-half
    const int NT   = j;                        // gate col-tile
    const int R0   = 32*gq;                    // batch row base
    const int w    = tid >> 6;                 // wave 0..15
    const int lane = tid & 63;
    const int cl   = lane & 15;                // MFMA A-row / C-col
    const int kg   = lane >> 4;                // MFMA k-quad
    const int g    = w >> 3;                   // row-tile group 0..1
    const int wk   = w & 7;                    // K-split index 0..7
    const int uu   = lane >> 4;                // pointwise unit-local
    const int bl   = lane & 15;                // pointwise batch-local

    __shared__ __align__(16) float zb[2][8][16][20]; // 20480
    __shared__ float spb[8][128];                  // 4096 (q partials, then score partials)
    __shared__ float qv[128];                      // 512
    __shared__ float pexpA[128];                   // 512
    __shared__ float h2s[256];                     // 1024
    __shared__ float red[16];                      // 64
    __shared__ float Vs[128];                      // 512
    __shared__ float embWs[256];                   // 1024
    __shared__ float embbs[256];                   // 1024
    __shared__ __align__(16) float ctxp[4][512];   // 8192  -> total ~37.4 KB

    // ---- LDS / register preloads ----
    float b2r = 0.0f; float2 wo2 = make_float2(0.f, 0.f);
    if(tid < 128){
        Vs[tid] = V[tid]; b2r = b2[tid];
        wo2 = make_float2(Wo[2*tid], Wo[2*tid+1]);
    }
    if(tid < 256){ embWs[tid] = embW[tid]; embbs[tid] = embb[tid]; }
    const float bVv = bVp[0], bov = bop[0];

    // ---- register-resident weight B-frags ----
    uint4 wfb[4];
    #pragma unroll
    for(int i = 0; i < 4; ++i){
        int kt = wk*4 + i;
        wfb[i] = *(const uint4*)((const char*)WbF + (((size_t)(kt*64 + NT)*64 + lane) << 4));
    }
    uint4 wfc[2];
    #pragma unroll
    for(int i = 0; i < 2; ++i){
        int kt = wk*2 + i;
        wfc[i] = *(const uint4*)((const char*)WcF + (((size_t)(kt*64 + NT)*64 + lane) << 4));
    }

    // ---- reducer-wave cell state + gate biases (waves 0 and 8) ----
    const int ug = 4*NT + uu;
    float bi1=0,bf1=0,bg1=0,bo1=0,bi2=0,bf2=0,bg2=0,bo2=0;
    float c1r = 0.0f, c2r = 0.0f;
    if(wk == 0){
        bi1 = bl1[ug]; bf1 = bl1[256+ug]; bg1 = bl1[512+ug]; bo1 = bl1[768+ug];
        bi2 = bl2[ug]; bf2 = bl2[256+ug]; bg2 = bl2[512+ug]; bo2 = bl2[768+ug];
        const int bb0 = R0 + 16*g + bl;
        c1r = c1_in[bb0*256 + ug];
        c2r = c2_in[bb0*256 + ug];
    }
    __syncthreads();

    for(int t = 0; t < 48; ++t){
        const int rpar = t & 1, wpar = rpar ^ 1;
        unsigned int* h1r = h1d + rpar*16384;
        unsigned int* h1w = h1d + wpar*16384;
        unsigned int* h2r = h2d + rpar*16384;
        unsigned int* h2w = h2d + wpar*16384;

        // ================= PHASE A : attention half + pred(t-1) =================
        if(tid < 128){
            unsigned int v = __hip_atomic_load(&h2r[ab*128 + tid], __ATOMIC_RELAXED, AGENT);
            float2 f = __half22float2(__builtin_bit_cast(__half2, v));
            h2s[2*tid] = f.x; h2s[2*tid+1] = f.y;
            float pv = f.x*wo2.x + f.y*wo2.y;
            #pragma unroll
            for(int off = 32; off >= 1; off >>= 1) pv += __shfl_xor(pv, off);
            if(lane == 0) red[8 + w] = pv;
        }
        __syncthreads();
        if(tid == 0 && t > 0 && sh == 0) out[ab*48 + (t-1)] = red[8] + red[9] + bov;
        // q partials: 8 k-groups x 128 u
        {
            const int u = tid & 127, kq = tid >> 7, k0 = kq*32;
            float a = 0.0f;
            #pragma unroll 8
            for(int k = k0; k < k0 + 32; ++k) a += h2s[k]*W2[k*128 + u];
            spb[kq][u] = a;
        }
        __syncthreads();
        if(tid < 128){
            float a = b2r;
            #pragma unroll
            for(int j2 = 0; j2 < 8; ++j2) a += spb[j2][tid];
            qv[tid] = a;
        }
        __syncthreads();
        // score partials over this block's s-half: 8 u-groups x 128 s
        {
            const int sl = tid & 127, uo = tid >> 7;
            const __half* kp = keysH + ((size_t)(ab*128 + uo*16))*256 + sh*128 + sl;
            float a = 0.0f;
            #pragma unroll 8
            for(int ui = 0; ui < 16; ++ui){
                const int u = uo*16 + ui;
                a += fast_tanh(__half2float(kp[(size_t)ui*256]) + qv[u]) * Vs[u];
            }
            spb[uo][sl] = a;
        }
        __syncthreads();
        // pexp (no max pass; |score| <= sum|V| ~ 28, fp32-safe) + partial sum
        if(tid < 128){
            float sc = bVv;
            #pragma unroll
            for(int j2 = 0; j2 < 8; ++j2) sc += spb[j2][tid];
            float p = __expf(sc);
            pexpA[tid] = p;
            float su = p;
            #pragma unroll
            for(int off = 32; off >= 1; off >>= 1) su += __shfl_xor(su, off);
            if(lane == 0) red[w] = su;
        }
        __syncthreads();
        if(tid == 0)
            __hip_atomic_store(&SU[ab*2 + sh], red[0] + red[1], __ATOMIC_RELAXED, AGENT);
        // unnormalized ctx partial: ALL 1024 threads, half2-vectorized,
        // 4 s-slices of 32 x (256 half2 = 512 e); 32 iters/thread
        {
            const int e2 = tid & 255, s4 = tid >> 8;
            float a0 = 0.0f, a1 = 0.0f;
            if(useEncH){
                const __half2* ep = (const __half2*)(encH
                    + ((size_t)(ab*256 + sh*128 + s4*32))*512 + 2*e2);
                #pragma unroll 8
                for(int si = 0; si < 32; ++si){
                    float att = pexpA[s4*32 + si];
                    float2 ev = __half22float2(ep[(size_t)si*256]);
                    a0 += att*ev.x; a1 += att*ev.y;
                }
            } else {
                const float* ep = enc + ((size_t)(ab*256 + sh*128 + s4*32))*512 + 2*e2;
                #pragma unroll 8
                for(int si = 0; si < 32; ++si){
                    float att = pexpA[s4*32 + si];
                    float2 ev = *(const float2*)(ep + (size_t)si*512);
                    a0 += att*ev.x; a1 += att*ev.y;
                }
            }
            *(float2*)&ctxp[s4][2*e2] = make_float2(a0, a1);
        }
        __syncthreads();
        if(tid < 512){
            float a = ctxp[0][tid] + ctxp[1][tid] + ctxp[2][tid] + ctxp[3][tid];
            __hip_atomic_store(&CTXU[((size_t)ab*2 + sh)*512 + tid], a, __ATOMIC_RELAXED, AGENT);
        }
        gbar(cnt, gq, 3*t + 0);

        // ================= PHASE B : LSTM1 (parallel row-tiles, 8-way K-split) =====
        {
            const int rowB = R0 + 16*g + cl;
            uint4 af[4];
            if(wk < 2){            // emb region: rank-1, recompute from consts
                const float x = xdec[rowB*48 + t];
                #pragma unroll
                for(int i = 0; i < 4; ++i){
                    const int K = wk*128 + 32*i + kg*8;
                    v8h hv;
                    #pragma unroll
                    for(int j2 = 0; j2 < 8; ++j2)
                        hv[j2] = (_Float16)fmaxf(x*embWs[K+j2] + embbs[K+j2], 0.0f);
                    af[i] = __builtin_bit_cast(uint4, hv);
                }
            } else if(wk < 6){     // ctx region: combine halves, deferred normalize
                u64 sv = __hip_atomic_load((u64*)(SU + rowB*2), __ATOMIC_RELAXED, AGENT);
                float2 ss = __builtin_bit_cast(float2, sv);
                float rn = 1.0f/(ss.x + ss.y);
                u64* cp = (u64*)(CTXU + (size_t)rowB*1024);
                #pragma unroll
                for(int i = 0; i < 4; ++i){
                    const int e0 = (wk-2)*128 + 32*i + kg*8;
                    u64 a0 = __hip_atomic_load(cp + (e0>>1),       __ATOMIC_RELAXED, AGENT);
                    u64 a1 = __hip_atomic_load(cp + (e0>>1) + 1,   __ATOMIC_RELAXED, AGENT);
                    u64 a2 = __hip_atomic_load(cp + (e0>>1) + 2,   __ATOMIC_RELAXED, AGENT);
                    u64 a3 = __hip_atomic_load(cp + (e0>>1) + 3,   __ATOMIC_RELAXED, AGENT);
                    u64 b0 = __hip_atomic_load(cp + 256 + (e0>>1),     __ATOMIC_RELAXED, AGENT);
                    u64 b1 = __hip_atomic_load(cp + 256 + (e0>>1) + 1, __ATOMIC_RELAXED, AGENT);
                    u64 b2v= __hip_atomic_load(cp + 256 + (e0>>1) + 2, __ATOMIC_RELAXED, AGENT);
                    u64 b3 = __hip_atomic_load(cp + 256 + (e0>>1) + 3, __ATOMIC_RELAXED, AGENT);
                    float2 fa0 = __builtin_bit_cast(float2, a0), fb0 = __builtin_bit_cast(float2, b0);
                    float2 fa1 = __builtin_bit_cast(float2, a1), fb1 = __builtin_bit_cast(float2, b1);
                    float2 fa2 = __builtin_bit_cast(float2, a2), fb2 = __builtin_bit_cast(float2, b2v);
                    float2 fa3 = __builtin_bit_cast(float2, a3), fb3 = __builtin_bit_cast(float2, b3);
                    v8h hv;
                    hv[0] = (_Float16)((fa0.x+fb0.x)*rn); hv[1] = (_Float16)((fa0.y+fb0.y)*rn);
                    hv[2] = (_Float16)((fa1.x+fb1.x)*rn); hv[3] = (_Float16)((fa1.y+fb1.y)*rn);
                    hv[4] = (_Float16)((fa2.x+fb2.x)*rn); hv[5] = (_Float16)((fa2.y+fb2.y)*rn);
                    hv[6] = (_Float16)((fa3.x+fb3.x)*rn); hv[7] = (_Float16)((fa3.y+fb3.y)*rn);
                    af[i] = __builtin_bit_cast(uint4, hv);
                }
            } else {               // h1(t-1) region: packed fp16 pairs via MALL
                const u64* hp = (const u64*)h1r + (size_t)rowB*64;
                #pragma unroll
                for(int i = 0; i < 4; ++i){
                    const int K0 = (wk-6)*128 + 32*i + kg*8;
                    u64 q0 = __hip_atomic_load((u64*)hp + (K0>>2),     __ATOMIC_RELAXED, AGENT);
                    u64 q1 = __hip_atomic_load((u64*)hp + (K0>>2) + 1, __ATOMIC_RELAXED, AGENT);
                    af[i] = make_uint4((unsigned int)q0, (unsigned int)(q0>>32),
                                       (unsigned int)q1, (unsigned int)(q1>>32));
                }
            }
            v4f acc = {0.0f, 0.0f, 0.0f, 0.0f};
            #pragma unroll
            for(int i = 0; i < 4; ++i)
                acc = __builtin_amdgcn_mfma_f32_16x16x32_f16(
                        __builtin_bit_cast(v8h, af[i]), __builtin_bit_cast(v8h, wfb[i]), acc, 0, 0, 0);
            #pragma unroll
            for(int r = 0; r < 4; ++r) zb[g][wk][kg*4 + r][cl] = acc[r];
            __syncthreads();
            if(wk == 0){
                v4f z = {0.0f, 0.0f, 0.0f, 0.0f};
                #pragma unroll
                for(int q = 0; q < 8; ++q) z += *(const v4f*)&zb[g][q][bl][uu*4];
                float cn = fast_sigm(z.y + bf1)*c1r + fast_sigm(z.x + bi1)*fast_tanh(z.z + bg1);
                c1r = cn;
                float hn = fast_sigm(z.w + bo1)*fast_tanh(cn);
                float hp2 = __shfl_xor(hn, 16);
                if((uu & 1) == 0){
                    __half2 ph = __floats2half2_rn(hn, hp2);
                    int bb = R0 + 16*g + bl;
                    __hip_atomic_store(&h1w[bb*128 + 2*NT + (uu >> 1)],
                                       __builtin_bit_cast(unsigned int, ph),
                                       __ATOMIC_RELAXED, AGENT);
                }
            }
        }
        gbar(cnt, gq, 3*t + 1);

        // ================= PHASE C : LSTM2 (parallel row-tiles, 8-way K-split) =====
        {
            const int rowB = R0 + 16*g + cl;
            uint4 af2[2];
            #pragma unroll
            for(int i = 0; i < 2; ++i){
                const int kt = wk*2 + i;
                const int K0 = kt*32 + kg*8;
                const u64* hp = (kt < 8) ? ((const u64*)h1w + (size_t)rowB*64 + (K0>>2))
                                         : ((const u64*)h2r + (size_t)rowB*64 + ((K0-256)>>2));
                u64 q0 = __hip_atomic_load((u64*)hp,     __ATOMIC_RELAXED, AGENT);
                u64 q1 = __hip_atomic_load((u64*)hp + 1, __ATOMIC_RELAXED, AGENT);
                af2[i] = make_uint4((unsigned int)q0, (unsigned int)(q0>>32),
                                    (unsigned int)q1, (unsigned int)(q1>>32));
            }
            v4f acc = {0.0f, 0.0f, 0.0f, 0.0f};
            #pragma unroll
            for(int i = 0; i < 2; ++i)
                acc = __builtin_amdgcn_mfma_f32_16x16x32_f16(
                        __builtin_bit_cast(v8h, af2[i]), __builtin_bit_cast(v8h, wfc[i]), acc, 0, 0, 0);
            #pragma unroll
            for(int r = 0; r < 4; ++r) zb[g][wk][kg*4 + r][cl] = acc[r];
            __syncthreads();
            if(wk == 0){
                v4f z = {0.0f, 0.0f, 0.0f, 0.0f};
                #pragma unroll
                for(int q = 0; q < 8; ++q) z += *(const v4f*)&zb[g][q][bl][uu*4];
                float cn = fast_sigm(z.y + bf2)*c2r + fast_sigm(z.x + bi2)*fast_tanh(z.z + bg2);
                c2r = cn;
                float hn = fast_sigm(z.w + bo2)*fast_tanh(cn);
                float hp2 = __shfl_xor(hn, 16);
                if((uu & 1) == 0){
                    __half2 ph = __floats2half2_rn(hn, hp2);
                    int bb = R0 + 16*g + bl;
                    __hip_atomic_store(&h2w[bb*128 + 2*NT + (uu >> 1)],
                                       __builtin_bit_cast(unsigned int, ph),
                                       __ATOMIC_RELAXED, AGENT);
                }
            }
        }
        gbar(cnt, gq, 3*t + 2);
    }

    // final pred (t=47): h2 at parity 0
    if(sh == 0){
        if(tid < 128){
            unsigned int v = __hip_atomic_load(&h2d[ab*128 + tid], __ATOMIC_RELAXED, AGENT);
            float2 f = __half22float2(__builtin_bit_cast(__half2, v));
            float pv = f.x*wo2.x + f.y*wo2.y;
            #pragma unroll
            for(int off = 32; off >= 1; off >>= 1) pv += __shfl_xor(pv, off);
            if(lane == 0) red[w] = pv;
        }
        __syncthreads();
        if(tid == 0) out[ab*48 + 47] = red[0] + red[1] + bov;
    }
}

extern "C" void kernel_launch(void* const* d_in, const int* in_sizes, int n_in,
                              void* d_out, int out_size, void* d_ws, size_t ws_size,
                              hipStream_t stream)
{
    const float* xdec = (const float*)d_in[0];
    const float* h1_in= (const float*)d_in[1];
    const float* c1_in= (const float*)d_in[2];
    const float* h2_in= (const float*)d_in[3];
    const float* c2_in= (const float*)d_in[4];
    const float* enc  = (const float*)d_in[5];
    const float* embW = (const float*)d_in[6];
    const float* embb = (const float*)d_in[7];
    const float* W1   = (const float*)d_in[8];
    const float* b1   = (const float*)d_in[9];
    const float* W2   = (const float*)d_in[10];
    const float* b2   = (const float*)d_in[11];
    const float* V    = (const float*)d_in[12];
    const float* bV   = (const float*)d_in[13];
    const float* Wx1  = (const float*)d_in[14];
    const float* Wh1  = (const float*)d_in[15];
    const float* bl1  = (const float*)d_in[16];
    const float* Wx2  = (const float*)d_in[17];
    const float* Wh2  = (const float*)d_in[18];
    const float* bl2  = (const float*)d_in[19];
    const float* Wo   = (const float*)d_in[20];
    const float* bo   = (const float*)d_in[21];

    if(ws_size < WS_CORE) return;

    char* ws = (char*)d_ws;
    __half* keysH = (__half*)(ws + OFF_KEYSH);
    __half* WbF   = (__half*)(ws + OFF_WBF);
    __half* WcF   = (__half*)(ws + OFF_WCF);
    float*  W1t   = (float*) (ws + OFF_W1T);
    float*  CTXU  = (float*) (ws + OFF_CTXU);
    float*  SU    = (float*) (ws + OFF_SU);
    unsigned int* h1d = (unsigned int*)(ws + OFF_H1);
    unsigned int* h2d = (unsigned int*)(ws + OFF_H2);
    int*    cnt   = (int*)   (ws + OFF_CNT);
    __half* encH  = (__half*)(ws + OFF_ENCH);

    const int useEncH = (ws_size >= WS_FULL) ? 1 : 0;
    const long long total = useEncH ? 18449408LL : 1672192LL;

    hipLaunchKernelGGL(setup_kernel, dim3(4096), dim3(256), 0, stream,
        Wx1, Wh1, Wx2, Wh2, W1, h1_in, h2_in, enc,
        WbF, WcF, W1t, h1d, h2d, cnt, encH, total);

    hipLaunchKernelGGL(keys_kernel, dim3(1024), dim3(256), 0, stream,
        enc, W1t, b1, keysH);

    hipLaunchKernelGGL(decoder_v8, dim3(256), dim3(1024), 0, stream,
        xdec, embW, embb, W2, b2, V, bV, Wo, bo, bl1, bl2,
        c1_in, c2_in, enc, encH, keysH, WbF, WcF, CTXU, SU,
        h1d, h2d, cnt, (float*)d_out, useEncH);
}

// Round 9
// 2128.225 us; speedup vs baseline: 1.0141x; 1.0141x over previous
//
#include <hip/hip_runtime.h>
#include <hip/hip_fp16.h>

#define AGENT __HIP_MEMORY_SCOPE_AGENT

typedef _Float16 v8h __attribute__((ext_vector_type(8)));
typedef float    v4f __attribute__((ext_vector_type(4)));
typedef unsigned long long u64;

// ---- workspace map (bytes) ----
#define OFF_KEYSH  0UL            // __half [128][128][256] (b,u,s)   = 8,388,608
#define OFF_WBF    8388608UL      // __half Wb B-frags, 4u+g perm: 32kt x 64nt x 64lane x 8 = 2,097,152
#define OFF_WCF    10485760UL     // __half Wc B-frags, 4u+g perm: 16kt x 64nt x 64lane x 8 = 1,048,576
#define OFF_W1T    11534336UL     // float [128 u][512 e]             =   262,144
#define OFF_CTXU   11796480UL     // float [128 b][2 half][512 e]     =   524,288
#define OFF_SU     12320768UL     // float [128 b][2 half]            =     1,024
#define OFF_H1     12321792UL     // uint  [2][128][128]              =   131,072
#define OFF_H2     12452864UL     // uint  [2][128][128]              =   131,072
#define OFF_CNT    12583936UL     // int[4 grp][256]: [0..143] masters, [160/176] subs = 4,096
#define WS_CORE    12588032UL
#define OFF_ENCH   12588032UL     // __half [128][256][512]           = 33,554,432
#define WS_FULL    46142464UL

static __device__ __forceinline__ float fast_tanh(float x){
    float e = __expf(2.0f*x);
    return 1.0f - 2.0f*__builtin_amdgcn_rcpf(e + 1.0f);
}
static __device__ __forceinline__ float fast_sigm(float x){
    return __builtin_amdgcn_rcpf(1.0f + __expf(-x));
}

// Group-local grid barrier: 64 blocks per group, 4 independent groups.
// Arrival: 2 sub-counters x 32 blocks (distinct 64-B lines); combiner
// (old==31) resets its sub-line then bumps the group's per-phase master;
// poll single master line (<2). Monotone masters, fresh per phase.
// s_waitcnt(0) drains relaxed agent stores pre-arrival (proven r4 pattern).
static __device__ __forceinline__ void gbar(int* cnt, int grp, int idx){
    __builtin_amdgcn_s_waitcnt(0);
    __syncthreads();
    if(threadIdx.x == 0){
        int* base = cnt + (grp << 8);
        int* sub  = base + 160 + (((blockIdx.x >> 5) & 1) << 4);
        int old = __hip_atomic_fetch_add(sub, 1, __ATOMIC_RELAXED, AGENT);
        if(old == 31){
            __hip_atomic_store(sub, 0, __ATOMIC_RELAXED, AGENT);
            __builtin_amdgcn_s_waitcnt(0);
            __hip_atomic_fetch_add(&base[idx], 1, __ATOMIC_RELAXED, AGENT);
        }
        while(__hip_atomic_load(&base[idx], __ATOMIC_RELAXED, AGENT) < 2)
            __builtin_amdgcn_s_sleep(1);
    }
    __syncthreads();
}

// ---------------- slim setup: permuted MFMA B-frag weights, W1t, state packing, counters
// (encH conversion moved to dedicated vectorized ench_kernel)
// WbF half idx = ((kt*64 + nt)*64 + lane)*8 + j ; c = nt*16 + (lane&15) (4u+g space)
//   n_raw = (c&3)*256 + (c>>2) ; k = kt*32 + (lane>>4)*8 + j
//   k<768 -> Wx1[k][n_raw] ([emb|ctx] rows), else Wh1[k-768][n_raw]
// WcF: kt 0..15 ; k<256 -> Wx2[k][n_raw], else Wh2[k-256][n_raw]  ([h1|h2])
__global__ __launch_bounds__(256) void setup_kernel(
    const float* __restrict__ Wx1, const float* __restrict__ Wh1,
    const float* __restrict__ Wx2, const float* __restrict__ Wh2,
    const float* __restrict__ W1,
    const float* __restrict__ h1_in, const float* __restrict__ h2_in,
    __half* __restrict__ WbF, __half* __restrict__ WcF, float* __restrict__ W1t,
    unsigned int* __restrict__ h1d, unsigned int* __restrict__ h2d,
    int* __restrict__ cnt)
{
    const long long total = 1672192LL;
    long long id0 = (long long)blockIdx.x*blockDim.x + threadIdx.x;
    long long stride = (long long)gridDim.x*blockDim.x;
    for(long long id = id0; id < total; id += stride){
        if(id < 1048576LL){                         // WbF
            int j = (int)(id & 7), lane = (int)((id >> 3) & 63);
            int tile = (int)(id >> 9);
            int nt = tile & 63, kt = tile >> 6;
            int c = nt*16 + (lane & 15);
            int n = (c & 3)*256 + (c >> 2);
            int k = kt*32 + (lane >> 4)*8 + j;
            float v = (k < 768) ? Wx1[k*1024 + n] : Wh1[(k-768)*1024 + n];
            WbF[id] = __float2half(v);
        } else if(id < 1572864LL){                  // WcF
            long long i2 = id - 1048576LL;
            int j = (int)(i2 & 7), lane = (int)((i2 >> 3) & 63);
            int tile = (int)(i2 >> 9);
            int nt = tile & 63, kt = tile >> 6;
            int c = nt*16 + (lane & 15);
            int n = (c & 3)*256 + (c >> 2);
            int k = kt*32 + (lane >> 4)*8 + j;
            float v = (k < 256) ? Wx2[k*1024 + n] : Wh2[(k-256)*1024 + n];
            WcF[i2] = __float2half(v);
        } else if(id < 1638400LL){                  // W1t[u][e]
            long long i3 = id - 1572864LL;
            int u = (int)(i3 >> 9), e = (int)(i3 & 511);
            W1t[i3] = W1[e*128 + u];
        } else if(id < 1654784LL){                  // h1d parity 0, packed fp16 pairs
            long long i4 = id - 1638400LL;
            int b = (int)(i4 >> 7), j = (int)(i4 & 127);
            __half2 p = __floats2half2_rn(h1_in[b*256 + 2*j], h1_in[b*256 + 2*j + 1]);
            h1d[i4] = __builtin_bit_cast(unsigned int, p);
        } else if(id < 1671168LL){                  // h2d parity 0
            long long i5 = id - 1654784LL;
            int b = (int)(i5 >> 7), j = (int)(i5 & 127);
            __half2 p = __floats2half2_rn(h2_in[b*256 + 2*j], h2_in[b*256 + 2*j + 1]);
            h2d[i5] = __builtin_bit_cast(unsigned int, p);
        } else {                                    // cnt[1024] zero
            cnt[(int)(id - 1671168LL)] = 0;
        }
    }
}

// ---------------- vectorized enc fp32 -> fp16: 8 elems/thread, 16B stores
// 16,777,216 halfs / 8 = 2,097,152 threads = 8192 blocks x 256 (exact fit)
__global__ __launch_bounds__(256) void ench_kernel(
    const float* __restrict__ enc, __half* __restrict__ encH)
{
    size_t id = ((size_t)blockIdx.x*256 + threadIdx.x)*8;
    float4 f0 = *(const float4*)(enc + id);
    float4 f1 = *(const float4*)(enc + id + 4);
    __half2 h0 = __floats2half2_rn(f0.x, f0.y);
    __half2 h1 = __floats2half2_rn(f0.z, f0.w);
    __half2 h2 = __floats2half2_rn(f1.x, f1.y);
    __half2 h3 = __floats2half2_rn(f1.z, f1.w);
    uint4 o = make_uint4(__builtin_bit_cast(unsigned int, h0),
                         __builtin_bit_cast(unsigned int, h1),
                         __builtin_bit_cast(unsigned int, h2),
                         __builtin_bit_cast(unsigned int, h3));
    *(uint4*)(encH + id) = o;
}

// ---------------- keys = enc @ W1 + b1, transposed fp16 keysH[b][u][s]
__global__ __launch_bounds__(256) void keys_kernel(
    const float* __restrict__ enc, const float* __restrict__ W1t,
    const float* __restrict__ b1, __half* __restrict__ keysH)
{
    const int bb = blockIdx.x;            // 1024 blocks
    const int b  = bb >> 3, sq = bb & 7;
    const int tid = threadIdx.x;
    const int u = tid & 127, sh = tid >> 7;
    const int s0 = sq*32 + sh*16;
    float acc[16];
    #pragma unroll
    for(int i = 0; i < 16; ++i) acc[i] = 0.0f;
    const float* wp = W1t + (size_t)u*512;
    const float* xp = enc + (size_t)(b*256 + s0)*512;
    for(int e = 0; e < 512; e += 4){
        float4 wv = *(const float4*)(wp + e);
        #pragma unroll
        for(int i = 0; i < 16; ++i){
            float4 xv = *(const float4*)(xp + (size_t)i*512 + e);
            acc[i] += wv.x*xv.x + wv.y*xv.y + wv.z*xv.z + wv.w*xv.w;
        }
    }
    const float bu = b1[u];
    __half* op = keysH + (size_t)(b*128 + u)*256 + s0;
    #pragma unroll
    for(int i = 0; i < 16; ++i) op[i] = __float2half(acc[i] + bu);
}

// ---------------- persistent decoder: 256 blocks x 1024 threads (~1/CU)
// UNCHANGED from round 8 (proven 1714us, absmax 0.001953).
// GROUP-LOCAL decomposition: gq = bid>>6 owns batches 32gq..32gq+31; j = bid&63.
// Attention: ab = 32gq + (j>>1), s-half sh = j&1; deferred softmax norm.
// LSTM: NT = j owns gate-cols 16j.. (4u+g perm) for the group's 32 rows;
// two 16-row tiles by parallel 8-wave groups (8-way K-split). All three
// per-step exchanges (CTXU/SU, h1, h2) are group-internal -> 64-block
// barriers, 4 independent groups. Weights register-resident as B-frags.
__global__ __launch_bounds__(1024) void decoder_v8(
    const float* __restrict__ xdec, const float* __restrict__ embW, const float* __restrict__ embb,
    const float* __restrict__ W2, const float* __restrict__ b2,
    const float* __restrict__ V, const float* __restrict__ bVp,
    const float* __restrict__ Wo, const float* __restrict__ bop,
    const float* __restrict__ bl1, const float* __restrict__ bl2,
    const float* __restrict__ c1_in, const float* __restrict__ c2_in,
    const float* __restrict__ enc, const __half* __restrict__ encH,
    const __half* __restrict__ keysH,
    const __half* __restrict__ WbF, const __half* __restrict__ WcF,
    float* CTXU, float* SU,
    unsigned int* h1d, unsigned int* h2d,
    int* cnt, float* __restrict__ out, int useEncH)
{
    const int tid  = threadIdx.x;
    const int bid  = blockIdx.x;
    const int gq   = bid >> 6;                 // group (32 batches)
    const int j    = bid & 63;                 // block within group
    const int ab   = 32*gq + (j >> 1);         // attention batch
    const int sh   = j & 1;                    // s-half
    const int NT   = j;                        // gate col-tile
    const int R0   = 32*gq;                    // batch row base
    const int w    = tid >> 6;                 // wave 0..15
    const int lane = tid & 63;
    const int cl   = lane & 15;                // MFMA A-row / C-col
    const int kg   = lane >> 4;                // MFMA k-quad
    const int g    = w >> 3;                   // row-tile group 0..1
    const int wk   = w & 7;                    // K-split index 0..7
    const int uu   = lane >> 4;                // pointwise unit-local
    const int bl   = lane & 15;                // pointwise batch-local

    __shared__ __align__(16) float zb[2][8][16][20]; // 20480
    __shared__ float spb[8][128];                  // 4096 (q partials, then score partials)
    __shared__ float qv[128];                      // 512
    __shared__ float pexpA[128];                   // 512
    __shared__ float h2s[256];                     // 1024
    __shared__ float red[16];                      // 64
    __shared__ float Vs[128];                      // 512
    __shared__ float embWs[256];                   // 1024
    __shared__ float embbs[256];                   // 1024
    __shared__ __align__(16) float ctxp[4][512];   // 8192  -> total ~37.4 KB

    // ---- LDS / register preloads ----
    float b2r = 0.0f; float2 wo2 = make_float2(0.f, 0.f);
    if(tid < 128){
        Vs[tid] = V[tid]; b2r = b2[tid];
        wo2 = make_float2(Wo[2*tid], Wo[2*tid+1]);
    }
    if(tid < 256){ embWs[tid] = embW[tid]; embbs[tid] = embb[tid]; }
    const float bVv = bVp[0], bov = bop[0];

    // ---- register-resident weight B-frags ----
    uint4 wfb[4];
    #pragma unroll
    for(int i = 0; i < 4; ++i){
        int kt = wk*4 + i;
        wfb[i] = *(const uint4*)((const char*)WbF + (((size_t)(kt*64 + NT)*64 + lane) << 4));
    }
    uint4 wfc[2];
    #pragma unroll
    for(int i = 0; i < 2; ++i){
        int kt = wk*2 + i;
        wfc[i] = *(const uint4*)((const char*)WcF + (((size_t)(kt*64 + NT)*64 + lane) << 4));
    }

    // ---- reducer-wave cell state + gate biases (waves 0 and 8) ----
    const int ug = 4*NT + uu;
    float bi1=0,bf1=0,bg1=0,bo1=0,bi2=0,bf2=0,bg2=0,bo2=0;
    float c1r = 0.0f, c2r = 0.0f;
    if(wk == 0){
        bi1 = bl1[ug]; bf1 = bl1[256+ug]; bg1 = bl1[512+ug]; bo1 = bl1[768+ug];
        bi2 = bl2[ug]; bf2 = bl2[256+ug]; bg2 = bl2[512+ug]; bo2 = bl2[768+ug];
        const int bb0 = R0 + 16*g + bl;
        c1r = c1_in[bb0*256 + ug];
        c2r = c2_in[bb0*256 + ug];
    }
    __syncthreads();

    for(int t = 0; t < 48; ++t){
        const int rpar = t & 1, wpar = rpar ^ 1;
        unsigned int* h1r = h1d + rpar*16384;
        unsigned int* h1w = h1d + wpar*16384;
        unsigned int* h2r = h2d + rpar*16384;
        unsigned int* h2w = h2d + wpar*16384;

        // ================= PHASE A : attention half + pred(t-1) =================
        if(tid < 128){
            unsigned int v = __hip_atomic_load(&h2r[ab*128 + tid], __ATOMIC_RELAXED, AGENT);
            float2 f = __half22float2(__builtin_bit_cast(__half2, v));
            h2s[2*tid] = f.x; h2s[2*tid+1] = f.y;
            float pv = f.x*wo2.x + f.y*wo2.y;
            #pragma unroll
            for(int off = 32; off >= 1; off >>= 1) pv += __shfl_xor(pv, off);
            if(lane == 0) red[8 + w] = pv;
        }
        __syncthreads();
        if(tid == 0 && t > 0 && sh == 0) out[ab*48 + (t-1)] = red[8] + red[9] + bov;
        // q partials: 8 k-groups x 128 u
        {
            const int u = tid & 127, kq = tid >> 7, k0 = kq*32;
            float a = 0.0f;
            #pragma unroll 8
            for(int k = k0; k < k0 + 32; ++k) a += h2s[k]*W2[k*128 + u];
            spb[kq][u] = a;
        }
        __syncthreads();
        if(tid < 128){
            float a = b2r;
            #pragma unroll
            for(int j2 = 0; j2 < 8; ++j2) a += spb[j2][tid];
            qv[tid] = a;
        }
        __syncthreads();
        // score partials over this block's s-half: 8 u-groups x 128 s
        {
            const int sl = tid & 127, uo = tid >> 7;
            const __half* kp = keysH + ((size_t)(ab*128 + uo*16))*256 + sh*128 + sl;
            float a = 0.0f;
            #pragma unroll 8
            for(int ui = 0; ui < 16; ++ui){
                const int u = uo*16 + ui;
                a += fast_tanh(__half2float(kp[(size_t)ui*256]) + qv[u]) * Vs[u];
            }
            spb[uo][sl] = a;
        }
        __syncthreads();
        // pexp (no max pass; |score| <= sum|V| ~ 28, fp32-safe) + partial sum
        if(tid < 128){
            float sc = bVv;
            #pragma unroll
            for(int j2 = 0; j2 < 8; ++j2) sc += spb[j2][tid];
            float p = __expf(sc);
            pexpA[tid] = p;
            float su = p;
            #pragma unroll
            for(int off = 32; off >= 1; off >>= 1) su += __shfl_xor(su, off);
            if(lane == 0) red[w] = su;
        }
        __syncthreads();
        if(tid == 0)
            __hip_atomic_store(&SU[ab*2 + sh], red[0] + red[1], __ATOMIC_RELAXED, AGENT);
        // unnormalized ctx partial: ALL 1024 threads, half2-vectorized,
        // 4 s-slices of 32 x (256 half2 = 512 e); 32 iters/thread
        {
            const int e2 = tid & 255, s4 = tid >> 8;
            float a0 = 0.0f, a1 = 0.0f;
            if(useEncH){
                const __half2* ep = (const __half2*)(encH
                    + ((size_t)(ab*256 + sh*128 + s4*32))*512 + 2*e2);
                #pragma unroll 8
                for(int si = 0; si < 32; ++si){
                    float att = pexpA[s4*32 + si];
                    float2 ev = __half22float2(ep[(size_t)si*256]);
                    a0 += att*ev.x; a1 += att*ev.y;
                }
            } else {
                const float* ep = enc + ((size_t)(ab*256 + sh*128 + s4*32))*512 + 2*e2;
                #pragma unroll 8
                for(int si = 0; si < 32; ++si){
                    float att = pexpA[s4*32 + si];
                    float2 ev = *(const float2*)(ep + (size_t)si*512);
                    a0 += att*ev.x; a1 += att*ev.y;
                }
            }
            *(float2*)&ctxp[s4][2*e2] = make_float2(a0, a1);
        }
        __syncthreads();
        if(tid < 512){
            float a = ctxp[0][tid] + ctxp[1][tid] + ctxp[2][tid] + ctxp[3][tid];
            __hip_atomic_store(&CTXU[((size_t)ab*2 + sh)*512 + tid], a, __ATOMIC_RELAXED, AGENT);
        }
        gbar(cnt, gq, 3*t + 0);

        // ================= PHASE B : LSTM1 (parallel row-tiles, 8-way K-split) =====
        {
            const int rowB = R0 + 16*g + cl;
            uint4 af[4];
            if(wk < 2){            // emb region: rank-1, recompute from consts
                const float x = xdec[rowB*48 + t];
                #pragma unroll
                for(int i = 0; i < 4; ++i){
                    const int K = wk*128 + 32*i + kg*8;
                    v8h hv;
                    #pragma unroll
                    for(int j2 = 0; j2 < 8; ++j2)
                        hv[j2] = (_Float16)fmaxf(x*embWs[K+j2] + embbs[K+j2], 0.0f);
                    af[i] = __builtin_bit_cast(uint4, hv);
                }
            } else if(wk < 6){     // ctx region: combine halves, deferred normalize
                u64 sv = __hip_atomic_load((u64*)(SU + rowB*2), __ATOMIC_RELAXED, AGENT);
                float2 ss = __builtin_bit_cast(float2, sv);
                float rn = 1.0f/(ss.x + ss.y);
                u64* cp = (u64*)(CTXU + (size_t)rowB*1024);
                #pragma unroll
                for(int i = 0; i < 4; ++i){
                    const int e0 = (wk-2)*128 + 32*i + kg*8;
                    u64 a0 = __hip_atomic_load(cp + (e0>>1),       __ATOMIC_RELAXED, AGENT);
                    u64 a1 = __hip_atomic_load(cp + (e0>>1) + 1,   __ATOMIC_RELAXED, AGENT);
                    u64 a2 = __hip_atomic_load(cp + (e0>>1) + 2,   __ATOMIC_RELAXED, AGENT);
                    u64 a3 = __hip_atomic_load(cp + (e0>>1) + 3,   __ATOMIC_RELAXED, AGENT);
                    u64 b0 = __hip_atomic_load(cp + 256 + (e0>>1),     __ATOMIC_RELAXED, AGENT);
                    u64 b1 = __hip_atomic_load(cp + 256 + (e0>>1) + 1, __ATOMIC_RELAXED, AGENT);
                    u64 b2v= __hip_atomic_load(cp + 256 + (e0>>1) + 2, __ATOMIC_RELAXED, AGENT);
                    u64 b3 = __hip_atomic_load(cp + 256 + (e0>>1) + 3, __ATOMIC_RELAXED, AGENT);
                    float2 fa0 = __builtin_bit_cast(float2, a0), fb0 = __builtin_bit_cast(float2, b0);
                    float2 fa1 = __builtin_bit_cast(float2, a1), fb1 = __builtin_bit_cast(float2, b1);
                    float2 fa2 = __builtin_bit_cast(float2, a2), fb2 = __builtin_bit_cast(float2, b2v);
                    float2 fa3 = __builtin_bit_cast(float2, a3), fb3 = __builtin_bit_cast(float2, b3);
                    v8h hv;
                    hv[0] = (_Float16)((fa0.x+fb0.x)*rn); hv[1] = (_Float16)((fa0.y+fb0.y)*rn);
                    hv[2] = (_Float16)((fa1.x+fb1.x)*rn); hv[3] = (_Float16)((fa1.y+fb1.y)*rn);
                    hv[4] = (_Float16)((fa2.x+fb2.x)*rn); hv[5] = (_Float16)((fa2.y+fb2.y)*rn);
                    hv[6] = (_Float16)((fa3.x+fb3.x)*rn); hv[7] = (_Float16)((fa3.y+fb3.y)*rn);
                    af[i] = __builtin_bit_cast(uint4, hv);
                }
            } else {               // h1(t-1) region: packed fp16 pairs via MALL
                const u64* hp = (const u64*)h1r + (size_t)rowB*64;
                #pragma unroll
                for(int i = 0; i < 4; ++i){
                    const int K0 = (wk-6)*128 + 32*i + kg*8;
                    u64 q0 = __hip_atomic_load((u64*)hp + (K0>>2),     __ATOMIC_RELAXED, AGENT);
                    u64 q1 = __hip_atomic_load((u64*)hp + (K0>>2) + 1, __ATOMIC_RELAXED, AGENT);
                    af[i] = make_uint4((unsigned int)q0, (unsigned int)(q0>>32),
                                       (unsigned int)q1, (unsigned int)(q1>>32));
                }
            }
            v4f acc = {0.0f, 0.0f, 0.0f, 0.0f};
            #pragma unroll
            for(int i = 0; i < 4; ++i)
                acc = __builtin_amdgcn_mfma_f32_16x16x32_f16(
                        __builtin_bit_cast(v8h, af[i]), __builtin_bit_cast(v8h, wfb[i]), acc, 0, 0, 0);
            #pragma unroll
            for(int r = 0; r < 4; ++r) zb[g][wk][kg*4 + r][cl] = acc[r];
            __syncthreads();
            if(wk == 0){
                v4f z = {0.0f, 0.0f, 0.0f, 0.0f};
                #pragma unroll
                for(int q = 0; q < 8; ++q) z += *(const v4f*)&zb[g][q][bl][uu*4];
                float cn = fast_sigm(z.y + bf1)*c1r + fast_sigm(z.x + bi1)*fast_tanh(z.z + bg1);
                c1r = cn;
                float hn = fast_sigm(z.w + bo1)*fast_tanh(cn);
                float hp2 = __shfl_xor(hn, 16);
                if((uu & 1) == 0){
                    __half2 ph = __floats2half2_rn(hn, hp2);
                    int bb = R0 + 16*g + bl;
                    __hip_atomic_store(&h1w[bb*128 + 2*NT + (uu >> 1)],
                                       __builtin_bit_cast(unsigned int, ph),
                                       __ATOMIC_RELAXED, AGENT);
                }
            }
        }
        gbar(cnt, gq, 3*t + 1);

        // ================= PHASE C : LSTM2 (parallel row-tiles, 8-way K-split) =====
        {
            const int rowB = R0 + 16*g + cl;
            uint4 af2[2];
            #pragma unroll
            for(int i = 0; i < 2; ++i){
                const int kt = wk*2 + i;
                const int K0 = kt*32 + kg*8;
                const u64* hp = (kt < 8) ? ((const u64*)h1w + (size_t)rowB*64 + (K0>>2))
                                         : ((const u64*)h2r + (size_t)rowB*64 + ((K0-256)>>2));
                u64 q0 = __hip_atomic_load((u64*)hp,     __ATOMIC_RELAXED, AGENT);
                u64 q1 = __hip_atomic_load((u64*)hp + 1, __ATOMIC_RELAXED, AGENT);
                af2[i] = make_uint4((unsigned int)q0, (unsigned int)(q0>>32),
                                    (unsigned int)q1, (unsigned int)(q1>>32));
            }
            v4f acc = {0.0f, 0.0f, 0.0f, 0.0f};
            #pragma unroll
            for(int i = 0; i < 2; ++i)
                acc = __builtin_amdgcn_mfma_f32_16x16x32_f16(
                        __builtin_bit_cast(v8h, af2[i]), __builtin_bit_cast(v8h, wfc[i]), acc, 0, 0, 0);
            #pragma unroll
            for(int r = 0; r < 4; ++r) zb[g][wk][kg*4 + r][cl] = acc[r];
            __syncthreads();
            if(wk == 0){
                v4f z = {0.0f, 0.0f, 0.0f, 0.0f};
                #pragma unroll
                for(int q = 0; q < 8; ++q) z += *(const v4f*)&zb[g][q][bl][uu*4];
                float cn = fast_sigm(z.y + bf2)*c2r + fast_sigm(z.x + bi2)*fast_tanh(z.z + bg2);
                c2r = cn;
                float hn = fast_sigm(z.w + bo2)*fast_tanh(cn);
                float hp2 = __shfl_xor(hn, 16);
                if((uu & 1) == 0){
                    __half2 ph = __floats2half2_rn(hn, hp2);
                    int bb = R0 + 16*g + bl;
                    __hip_atomic_store(&h2w[bb*128 + 2*NT + (uu >> 1)],
                                       __builtin_bit_cast(unsigned int, ph),
                                       __ATOMIC_RELAXED, AGENT);
                }
            }
        }
        gbar(cnt, gq, 3*t + 2);
    }

    // final pred (t=47): h2 at parity 0
    if(sh == 0){
        if(tid < 128){
            unsigned int v = __hip_atomic_load(&h2d[ab*128 + tid], __ATOMIC_RELAXED, AGENT);
            float2 f = __half22float2(__builtin_bit_cast(__half2, v));
            float pv = f.x*wo2.x + f.y*wo2.y;
            #pragma unroll
            for(int off = 32; off >= 1; off >>= 1) pv += __shfl_xor(pv, off);
            if(lane == 0) red[w] = pv;
        }
        __syncthreads();
        if(tid == 0) out[ab*48 + 47] = red[0] + red[1] + bov;
    }
}

extern "C" void kernel_launch(void* const* d_in, const int* in_sizes, int n_in,
                              void* d_out, int out_size, void* d_ws, size_t ws_size,
                              hipStream_t stream)
{
    const float* xdec = (const float*)d_in[0];
    const float* h1_in= (const float*)d_in[1];
    const float* c1_in= (const float*)d_in[2];
    const float* h2_in= (const float*)d_in[3];
    const float* c2_in= (const float*)d_in[4];
    const float* enc  = (const float*)d_in[5];
    const float* embW = (const float*)d_in[6];
    const float* embb = (const float*)d_in[7];
    const float* W1   = (const float*)d_in[8];
    const float* b1   = (const float*)d_in[9];
    const float* W2   = (const float*)d_in[10];
    const float* b2   = (const float*)d_in[11];
    const float* V    = (const float*)d_in[12];
    const float* bV   = (const float*)d_in[13];
    const float* Wx1  = (const float*)d_in[14];
    const float* Wh1  = (const float*)d_in[15];
    const float* bl1  = (const float*)d_in[16];
    const float* Wx2  = (const float*)d_in[17];
    const float* Wh2  = (const float*)d_in[18];
    const float* bl2  = (const float*)d_in[19];
    const float* Wo   = (const float*)d_in[20];
    const float* bo   = (const float*)d_in[21];

    if(ws_size < WS_CORE) return;

    char* ws = (char*)d_ws;
    __half* keysH = (__half*)(ws + OFF_KEYSH);
    __half* WbF   = (__half*)(ws + OFF_WBF);
    __half* WcF   = (__half*)(ws + OFF_WCF);
    float*  W1t   = (float*) (ws + OFF_W1T);
    float*  CTXU  = (float*) (ws + OFF_CTXU);
    float*  SU    = (float*) (ws + OFF_SU);
    unsigned int* h1d = (unsigned int*)(ws + OFF_H1);
    unsigned int* h2d = (unsigned int*)(ws + OFF_H2);
    int*    cnt   = (int*)   (ws + OFF_CNT);
    __half* encH  = (__half*)(ws + OFF_ENCH);

    const int useEncH = (ws_size >= WS_FULL) ? 1 : 0;

    hipLaunchKernelGGL(setup_kernel, dim3(2048), dim3(256), 0, stream,
        Wx1, Wh1, Wx2, Wh2, W1, h1_in, h2_in,
        WbF, WcF, W1t, h1d, h2d, cnt);

    if(useEncH)
        hipLaunchKernelGGL(ench_kernel, dim3(8192), dim3(256), 0, stream, enc, encH);

    hipLaunchKernelGGL(keys_kernel, dim3(1024), dim3(256), 0, stream,
        enc, W1t, b1, keysH);

    hipLaunchKernelGGL(decoder_v8, dim3(256), dim3(1024), 0, stream,
        xdec, embW, embb, W2, b2, V, bV, Wo, bo, bl1, bl2,
        c1_in, c2_in, enc, encH, keysH, WbF, WcF, CTXU, SU,
        h1d, h2d, cnt, (float*)d_out, useEncH);
}